// Round 9
// baseline (221.945 us; speedup 1.0000x reference)
//
#include <hip/hip_runtime.h>
#include <cstdint>
#include <cstddef>

typedef __bf16 bf16;
typedef __attribute__((ext_vector_type(8))) __bf16 bf16x8;
typedef __attribute__((ext_vector_type(4))) __bf16 bf16x4;
typedef __attribute__((ext_vector_type(4))) float f32x4;

#define ADIM 1024
#define ASEQ 2048
#define ABATCH 8

__device__ __forceinline__ void gload_lds16(const void* g, void* l) {
  __builtin_amdgcn_global_load_lds(
      (const __attribute__((address_space(1))) void*)g,
      (__attribute__((address_space(3))) void*)l,
      16, 0, 0);
}

__device__ __forceinline__ f32x4 mfma16(bf16x8 a, bf16x8 b, f32x4 c) {
  return __builtin_amdgcn_mfma_f32_16x16x32_bf16(a, b, c, 0, 0, 0);
}

// ------- merged prep: cast x (blocks 0..2047) + transpose weights (2048..3071) -------
__global__ __launch_bounds__(256) void k_prep(
    const float* __restrict__ x, bf16* __restrict__ xb, int n4,
    const float* __restrict__ Wq, const float* __restrict__ Wk,
    const float* __restrict__ Wv, const float* __restrict__ Wo,
    bf16* __restrict__ WcT, bf16* __restrict__ WoT) {
  if (blockIdx.x < 2048) {
    int i = blockIdx.x * blockDim.x + threadIdx.x;
    int stride = 2048 * blockDim.x;
    for (; i < n4; i += stride) {
      float4 f = ((const float4*)x)[i];
      bf16x4 o = { (bf16)f.x, (bf16)f.y, (bf16)f.z, (bf16)f.w };
      ((bf16x4*)xb)[i] = o;
    }
    return;
  }
  const int b = blockIdx.x - 2048;
  const int which = b >> 8, t = b & 255;
  const int n0 = (t & 15) * 64, k0 = (t >> 4) * 64;
  const float* W = (which == 0) ? Wq : (which == 1) ? Wk : (which == 2) ? Wv : Wo;
  bf16* out = (which < 3) ? (WcT + (size_t)which * ADIM * ADIM) : WoT;

  __shared__ float tile[64][69];
  const int r = threadIdx.x >> 4, c4 = (threadIdx.x & 15) * 4;
#pragma unroll
  for (int p = 0; p < 4; ++p) {
    float4 f = *(const float4*)&W[(size_t)(k0 + p * 16 + r) * ADIM + n0 + c4];
    tile[p * 16 + r][c4 + 0] = f.x;
    tile[p * 16 + r][c4 + 1] = f.y;
    tile[p * 16 + r][c4 + 2] = f.z;
    tile[p * 16 + r][c4 + 3] = f.w;
  }
  __syncthreads();
#pragma unroll
  for (int p = 0; p < 4; ++p) {
    const int nn = p * 16 + r;
    bf16x4 o;
#pragma unroll
    for (int j = 0; j < 4; ++j) o[j] = (bf16)tile[c4 + j][nn];
    *(bf16x4*)&out[(size_t)(n0 + nn) * ADIM + k0 + c4] = o;
  }
}

// ====== 256x256-tile BK=64 GEMM, double-buffered, 16 steps, 1 fence/step =====
// Body identical to the passing r8 kernel. NEW: XCD-PAIR locality mapping --
// XCD pair p owns bx in {p*ntn/4 .. +ntn/4-1} (B slice <= 1.5 MB -> L2-resident
// per XCD) and walks all by with consecutive dispatch sharing by (A-band hot).
// flat%8 = XCD [m09]; pair=(flat%8)>>1; j=(flat>>3)*2+(flat&1) in [0,2*grid/8);
// bx = pair*bpp + j%bpp, by = j/bpp.  Bijective when grid%8==0 and ntn%4==0.
template<int MODE>
__global__ __launch_bounds__(512, 2) void k_gemm64(
    const bf16* __restrict__ A, const bf16* __restrict__ BT,
    const float* __restrict__ bias0, const float* __restrict__ bias1,
    const float* __restrict__ bias2,
    bf16* __restrict__ Qo, bf16* __restrict__ Ko, bf16* __restrict__ Vto,
    float* __restrict__ outF, int ntn)
{
  constexpr int K = 1024;
  constexpr int KT = K / 64;   // 16 steps of BK=64
  const int flat = blockIdx.x;
  const int pair = (flat & 7) >> 1;
  const int j = ((flat >> 3) << 1) + (flat & 1);
  const int bpp = ntn >> 2;                       // bx per pair
  const int bx = pair * bpp + j % bpp;
  const int by = j / bpp;
  const int m0 = by * 256, n0 = bx * 256;

  const int tid = threadIdx.x;
  const int l = tid & 63, w = tid >> 6;
  const int wm = w >> 2, wn = w & 3;     // 2M x 4N
  const int lr = l & 15, kg = l >> 4;    // kg in 0..3

  __shared__ alignas(16) bf16 sA[2][256 * 64];   // 64 KiB
  __shared__ alignas(16) bf16 sB[2][256 * 64];   // 64 KiB

  f32x4 acc[8][4] = {};

  // swizzled ds_read byte offsets for kh=0 (kh=1: offset ^ 64)
  int oA[8], oB[4];
#pragma unroll
  for (int i = 0; i < 8; ++i) {
    int r = wm * 128 + i * 16 + lr;
    oA[i] = (r * 8 + (kg ^ (r & 7))) * 16;
  }
#pragma unroll
  for (int jj = 0; jj < 4; ++jj) {
    int r = wn * 64 + jj * 16 + lr;
    oB[jj] = (r * 8 + (kg ^ (r & 7))) * 16;
  }

  auto stA = [&](int c, int kt, int chunk) {
    int s = chunk * 512 + tid;                    // linear 16B slot
    int prow = s >> 3, ps = s & 7;
    int lc = ps ^ (prow & 7);                     // inverse swizzle on source
    gload_lds16(A + (size_t)(m0 + prow) * K + kt * 64 + lc * 8,
                &sA[c][(size_t)s * 8]);
  };
  auto stB = [&](int c, int kt, int chunk) {
    int s = chunk * 512 + tid;
    int prow = s >> 3, ps = s & 7;
    int lc = ps ^ (prow & 7);
    gload_lds16(BT + (size_t)(n0 + prow) * K + kt * 64 + lc * 8,
                &sB[c][(size_t)s * 8]);
  };

  // prologue: tile 0 into buf 0
#pragma unroll
  for (int ch = 0; ch < 4; ++ch) { stA(0, 0, ch); stB(0, 0, ch); }
  asm volatile("s_waitcnt vmcnt(0)\n\ts_barrier" ::: "memory");

  for (int t = 0; t < KT; ++t) {
    const int c = t & 1;
    const char* bA = (const char*)&sA[c][0];
    const char* bB = (const char*)&sB[c][0];

    bf16x8 af[8], bfr[4];
    // ---- phase 0: k 0..31 ----
#pragma unroll
    for (int i = 0; i < 8; ++i) af[i] = *(const bf16x8*)(bA + oA[i]);
#pragma unroll
    for (int jj = 0; jj < 4; ++jj) bfr[jj] = *(const bf16x8*)(bB + oB[jj]);

    if (t + 1 < KT) {
#pragma unroll
      for (int ch = 0; ch < 4; ++ch) { stA(c ^ 1, t + 1, ch); stB(c ^ 1, t + 1, ch); }
    }

    __builtin_amdgcn_s_setprio(1);
#pragma unroll
    for (int i = 0; i < 8; ++i)
#pragma unroll
      for (int jj = 0; jj < 4; ++jj)
        acc[i][jj] = mfma16(af[i], bfr[jj], acc[i][jj]);
    __builtin_amdgcn_s_setprio(0);

    // ---- phase 1: k 32..63 ----
#pragma unroll
    for (int i = 0; i < 8; ++i) af[i] = *(const bf16x8*)(bA + (oA[i] ^ 64));
#pragma unroll
    for (int jj = 0; jj < 4; ++jj) bfr[jj] = *(const bf16x8*)(bB + (oB[jj] ^ 64));

    __builtin_amdgcn_s_setprio(1);
#pragma unroll
    for (int i = 0; i < 8; ++i)
#pragma unroll
      for (int jj = 0; jj < 4; ++jj)
        acc[i][jj] = mfma16(af[i], bfr[jj], acc[i][jj]);
    __builtin_amdgcn_s_setprio(0);

    asm volatile("s_waitcnt vmcnt(0)\n\ts_barrier" ::: "memory");
  }

  // ---- epilogue ----
  const int cb = n0 >> 10;          // uniform per block (256 | 1024)
#pragma unroll
  for (int i = 0; i < 8; ++i) {
#pragma unroll
    for (int jj = 0; jj < 4; ++jj) {
      const int n = n0 + wn * 64 + jj * 16 + lr;
      const int m0r = m0 + wm * 128 + i * 16 + kg * 4;
      if (MODE == 0) {
        const int nn = n & 1023;
        if (cb == 0) {
          const float b_ = bias0[nn];
#pragma unroll
          for (int r = 0; r < 4; ++r)
            Qo[(size_t)(m0r + r) * ADIM + nn] = (bf16)(acc[i][jj][r] + b_);
        } else if (cb == 1) {
          const float b_ = bias1[nn];
#pragma unroll
          for (int r = 0; r < 4; ++r) {
            float v = acc[i][jj][r] + b_;
            Ko[(size_t)(m0r + r) * ADIM + nn] = (bf16)(v > 0.f ? v + 1.f : __expf(v));
          }
        } else {
          const float b_ = bias2[nn];
          const int bb = m0r >> 11, t0c = m0r & 2047;
          bf16x4 pk;
#pragma unroll
          for (int r = 0; r < 4; ++r) pk[r] = (bf16)(acc[i][jj][r] + b_);
          *(bf16x4*)&Vto[((size_t)bb * ADIM + nn) * ASEQ + t0c] = pk;
        }
      } else {
        const float b_ = bias0[n];
#pragma unroll
        for (int r = 0; r < 4; ++r)
          outF[(size_t)(m0r + r) * ADIM + n] = acc[i][jj][r] + b_;
      }
    }
  }
}

// --------- windowed decay attention: one (batch, 64-row q-tile) per WG ---------
__global__ __launch_bounds__(256) void k_attn(
    const bf16* __restrict__ Qg, const bf16* __restrict__ Kg,
    const bf16* __restrict__ Vt, bf16* __restrict__ Rb,
    const float* __restrict__ decay_param)
{
  const int b = blockIdx.y;
  const int T0 = blockIdx.x * 64;
  const int tid = threadIdx.x;
  const int l = tid & 63, w = tid >> 6;
  const int lr = l & 15, lk = (l >> 4) * 8;

  const float dp = decay_param[0];
  const float decay = 1.f / (1.f + __expf(-dp));
  const float l2d = __log2f(decay);

  __shared__ alignas(16) bf16 lQ[2][64 * 32];
  __shared__ alignas(16) bf16 lK[2][128 * 32];
  __shared__ alignas(16) bf16 lV[2][128 * 32];
  __shared__ alignas(16) bf16 lP[64 * 136];

  const bf16* Qb = Qg + (size_t)(b * ASEQ + T0) * ADIM;

  auto stageQK = [&](int buf, int k0) {
    {
      const bf16* g = Qb + (size_t)(w * 16 + (l >> 2)) * ADIM + k0 + (l & 3) * 8;
      gload_lds16(g, &lQ[buf][w * 16 * 32]);
    }
#pragma unroll
    for (int cc = 0; cc < 2; ++cc) {
      int c = 2 * w + cc;
      int sg = T0 - 64 + c * 16 + (l >> 2);
      if (sg < 0) sg = 0;
      const bf16* g = Kg + (size_t)(b * ASEQ + sg) * ADIM + k0 + (l & 3) * 8;
      gload_lds16(g, &lK[buf][c * 16 * 32]);
    }
  };

  f32x4 sc[4][2] = {};
  stageQK(0, 0);
  __syncthreads();
  for (int kt = 0; kt < 32; ++kt) {
    int cur = kt & 1;
    if (kt + 1 < 32) stageQK(cur ^ 1, (kt + 1) * 32);
    bf16x8 af[4], bfr[2];
#pragma unroll
    for (int i = 0; i < 4; ++i)
      af[i] = *(const bf16x8*)&lQ[cur][(i * 16 + lr) * 32 + lk];
#pragma unroll
    for (int j = 0; j < 2; ++j)
      bfr[j] = *(const bf16x8*)&lK[cur][(w * 32 + j * 16 + lr) * 32 + lk];
#pragma unroll
    for (int i = 0; i < 4; ++i)
#pragma unroll
      for (int j = 0; j < 2; ++j)
        sc[i][j] = mfma16(af[i], bfr[j], sc[i][j]);
    __syncthreads();
  }

  const int er = (l >> 4) * 4, ec = l & 15;
#pragma unroll
  for (int i = 0; i < 4; ++i)
#pragma unroll
    for (int j = 0; j < 2; ++j)
#pragma unroll
      for (int r = 0; r < 4; ++r) {
        int tl = i * 16 + er + r;
        int sl = w * 32 + j * 16 + ec;
        int sg = T0 - 64 + sl;
        int delta = (T0 + tl) - 1 - sg;
        float wgt = (delta >= 0 && delta < 64 && sg >= 0)
                        ? exp2f((float)delta * l2d) : 0.f;
        lP[tl * 136 + sl] = (bf16)(sc[i][j][r] * wgt);
      }

  auto stageV = [&](int buf, int g) {
    int nc = g >> 2, ks = g & 3;
#pragma unroll
    for (int cc = 0; cc < 2; ++cc) {
      int c = 2 * w + cc;
      int drow = nc * 128 + c * 16 + (l >> 2);
      int scol = T0 - 64 + ks * 32 + (l & 3) * 8;
      if (scol < 0) scol = 0;
      const bf16* gv = Vt + ((size_t)b * ADIM + drow) * ASEQ + scol;
      gload_lds16(gv, &lV[buf][c * 16 * 32]);
    }
  };

  f32x4 o[4][2] = {};
  stageV(0, 0);
  __syncthreads();

  for (int g = 0; g < 32; ++g) {
    int cur = g & 1;
    if (g + 1 < 32) stageV(cur ^ 1, g + 1);
    int nc = g >> 2, ks = g & 3;
    bf16x8 af[4], bfr[2];
#pragma unroll
    for (int i = 0; i < 4; ++i)
      af[i] = *(const bf16x8*)&lP[(i * 16 + lr) * 136 + ks * 32 + lk];
#pragma unroll
    for (int j = 0; j < 2; ++j)
      bfr[j] = *(const bf16x8*)&lV[cur][(w * 32 + j * 16 + lr) * 32 + lk];
#pragma unroll
    for (int i = 0; i < 4; ++i)
#pragma unroll
      for (int j = 0; j < 2; ++j)
        o[i][j] = mfma16(af[i], bfr[j], o[i][j]);
    if (ks == 3) {
#pragma unroll
      for (int i = 0; i < 4; ++i)
#pragma unroll
        for (int j = 0; j < 2; ++j) {
#pragma unroll
          for (int r = 0; r < 4; ++r) {
            int tl = i * 16 + er + r;
            int dl = nc * 128 + w * 32 + j * 16 + ec;
            Rb[(size_t)(b * ASEQ + T0 + tl) * ADIM + dl] = (bf16)o[i][j][r];
          }
#pragma unroll
          for (int r = 0; r < 4; ++r) o[i][j][r] = 0.f;
        }
    }
    __syncthreads();
  }
}

extern "C" void kernel_launch(void* const* d_in, const int* in_sizes, int n_in,
                              void* d_out, int out_size, void* d_ws, size_t ws_size,
                              hipStream_t stream) {
  const float* x  = (const float*)d_in[0];
  const float* Wq = (const float*)d_in[1];
  const float* bq = (const float*)d_in[2];
  const float* Wk = (const float*)d_in[3];
  const float* bk = (const float*)d_in[4];
  const float* Wv = (const float*)d_in[5];
  const float* bv = (const float*)d_in[6];
  const float* Wo = (const float*)d_in[7];
  const float* bo = (const float*)d_in[8];
  const float* dp = (const float*)d_in[9];
  float* out = (float*)d_out;

  char* ws = (char*)d_ws;
  bf16* Xb  = (bf16*)(ws + ((size_t)0 << 20));    // [16384][1024]
  bf16* Qb  = (bf16*)(ws + ((size_t)32 << 20));
  bf16* Kb  = (bf16*)(ws + ((size_t)64 << 20));
  bf16* Vtb = (bf16*)(ws + ((size_t)96 << 20));   // [8][1024][2048]
  bf16* Rbb = (bf16*)(ws + ((size_t)128 << 20));
  bf16* WcT = (bf16*)(ws + ((size_t)160 << 20));  // [3072][1024]
  bf16* WoT = (bf16*)(ws + ((size_t)166 << 20));  // [1024][1024]

  const int M = ABATCH * ASEQ;  // 16384

  k_prep<<<3072, 256, 0, stream>>>(x, Xb, (M * ADIM) / 4,
                                   Wq, Wk, Wv, Wo, WcT, WoT);
  k_gemm64<0><<<768, 512, 0, stream>>>(
      Xb, WcT, bq, bk, bv, Qb, Kb, Vtb, nullptr, 12);
  k_attn<<<dim3(32, 8), 256, 0, stream>>>(Qb, Kb, Vtb, Rbb, dp);
  k_gemm64<1><<<256, 512, 0, stream>>>(
      Rbb, WoT, bo, nullptr, nullptr, nullptr, nullptr, nullptr, out, 4);
}

// Round 10
// 213.283 us; speedup vs baseline: 1.0406x; 1.0406x over previous
//
#include <hip/hip_runtime.h>
#include <cstdint>
#include <cstddef>

typedef __bf16 bf16;
typedef __attribute__((ext_vector_type(8))) __bf16 bf16x8;
typedef __attribute__((ext_vector_type(4))) __bf16 bf16x4;
typedef __attribute__((ext_vector_type(4))) float f32x4;

#define ADIM 1024
#define ASEQ 2048
#define ABATCH 8

__device__ __forceinline__ void gload_lds16(const void* g, void* l) {
  __builtin_amdgcn_global_load_lds(
      (const __attribute__((address_space(1))) void*)g,
      (__attribute__((address_space(3))) void*)l,
      16, 0, 0);
}

__device__ __forceinline__ f32x4 mfma16(bf16x8 a, bf16x8 b, f32x4 c) {
  return __builtin_amdgcn_mfma_f32_16x16x32_bf16(a, b, c, 0, 0, 0);
}

// ------- merged prep: cast x (blocks 0..2047) + transpose weights (2048..3071) -------
__global__ __launch_bounds__(256) void k_prep(
    const float* __restrict__ x, bf16* __restrict__ xb, int n4,
    const float* __restrict__ Wq, const float* __restrict__ Wk,
    const float* __restrict__ Wv, const float* __restrict__ Wo,
    bf16* __restrict__ WcT, bf16* __restrict__ WoT) {
  if (blockIdx.x < 2048) {
    int i = blockIdx.x * blockDim.x + threadIdx.x;
    int stride = 2048 * blockDim.x;
    for (; i < n4; i += stride) {
      float4 f = ((const float4*)x)[i];
      bf16x4 o = { (bf16)f.x, (bf16)f.y, (bf16)f.z, (bf16)f.w };
      ((bf16x4*)xb)[i] = o;
    }
    return;
  }
  const int b = blockIdx.x - 2048;
  const int which = b >> 8, t = b & 255;
  const int n0 = (t & 15) * 64, k0 = (t >> 4) * 64;
  const float* W = (which == 0) ? Wq : (which == 1) ? Wk : (which == 2) ? Wv : Wo;
  bf16* out = (which < 3) ? (WcT + (size_t)which * ADIM * ADIM) : WoT;

  __shared__ float tile[64][69];
  const int r = threadIdx.x >> 4, c4 = (threadIdx.x & 15) * 4;
#pragma unroll
  for (int p = 0; p < 4; ++p) {
    float4 f = *(const float4*)&W[(size_t)(k0 + p * 16 + r) * ADIM + n0 + c4];
    tile[p * 16 + r][c4 + 0] = f.x;
    tile[p * 16 + r][c4 + 1] = f.y;
    tile[p * 16 + r][c4 + 2] = f.z;
    tile[p * 16 + r][c4 + 3] = f.w;
  }
  __syncthreads();
#pragma unroll
  for (int p = 0; p < 4; ++p) {
    const int nn = p * 16 + r;
    bf16x4 o;
#pragma unroll
    for (int j = 0; j < 4; ++j) o[j] = (bf16)tile[c4 + j][nn];
    *(bf16x4*)&out[(size_t)(n0 + nn) * ADIM + k0 + c4] = o;
  }
}

// ======== 256x256 BK=64 GEMM, 8-phase quadrant schedule (m201-style) ========
// 512 threads = 8 waves (2M x 4N), per-wave C = 128x64 = acc[8][4].
// LDS = [2 half][2 dbuf] x 16KB for A and B = 128 KiB.
//   A-half h = quadrant row group {r: ((r>>6)&1)==h}; hrow=(r&63)|((r>>7)<<6).
//   B-half h = {n: ((n>>5)&1)==h};                   hnrow=(n&31)|((n>>6)<<5).
// Tile t uses dbuf d=t&1. Phases (2 barriers each):
//   p1: read af[0..3](A-h0,12B reads incl bf[0..1](B-h0)); stage A-h1(t+1),B-h0(t+1);
//       bar; 16 MFMA acc[0..3][0..1]; vmcnt(4)+bar
//   p2: read bf[2..3](B-h1); stage B-h1(t+1); bar; 16 MFMA acc[0..3][2..3]; bar
//   p3: read af[4..7](A-h1); stage A-h0(t+2)->dbuf d; bar; 16 MFMA acc[4..7][2..3]; bar
//   p4: no reads (bf[0..1] live since p1); bar; 16 MFMA acc[4..7][0..1]; vmcnt(4)+bar
// Ledger (steady): queue at end-p4 = [Ah1(t+1)2,Bh0(t+1)2,Bh1(t+1)2,Ah0(t+2)2];
//   vmcnt(4) retires Ah1(t+1),Bh0(t+1) (+ everything older) -> p1/p3 of t+1 OK.
//   end-p1 vmcnt(4) retires Bh1(t)2+Ah0(t+1)2 -> p2 of t OK. Never drains to 0.
// WAR: each stage target's last slot-read is >=1 full phase earlier, and stages
//   are issued only after the wave passed that phase's trailing barrier.
// Tail: stages guarded; t>=KT-2 uses vmcnt(0) at both wait points.
// Swizzle: 16B slot s' = c16 ^ (hrow&7), inverse applied on global source.
template<int MODE>
__global__ __launch_bounds__(512, 2) void k_g8(
    const bf16* __restrict__ A, const bf16* __restrict__ BT,
    const float* __restrict__ bias0, const float* __restrict__ bias1,
    const float* __restrict__ bias2,
    bf16* __restrict__ Qo, bf16* __restrict__ Ko, bf16* __restrict__ Vto,
    float* __restrict__ outF, int ntn)
{
  constexpr int K = 1024;
  constexpr int KT = K / 64;   // 16
  const int nwg = gridDim.x;
  const int cpx = nwg >> 3;
  const int flat = blockIdx.x;
  const int sw = (flat & 7) * cpx + (flat >> 3);   // grid % 8 == 0 (bijective)
  const int bx = sw % ntn, by = sw / ntn;
  const int m0 = by * 256, n0 = bx * 256;

  const int tid = threadIdx.x;
  const int l = tid & 63, w = tid >> 6;
  const int wm = w >> 2, wn = w & 3;     // 2M x 4N
  const int lr = l & 15, kg = l >> 4;    // kg 0..3

  __shared__ alignas(16) bf16 sA[2][2][128 * 64];   // [half][dbuf] 64 KiB
  __shared__ alignas(16) bf16 sB[2][2][128 * 64];   // 64 KiB

  f32x4 acc[8][4] = {};

  // read byte offsets within a half-slot (i&3 / j&1 index; half picks buffer)
  int oA[4][2], oB[2][2];
#pragma unroll
  for (int i = 0; i < 4; ++i) {
    int hrow = wm * 64 + i * 16 + lr;
#pragma unroll
    for (int ks = 0; ks < 2; ++ks) {
      int c16 = ks * 4 + kg;
      oA[i][ks] = (hrow * 8 + (c16 ^ (hrow & 7))) * 16;
    }
  }
#pragma unroll
  for (int j = 0; j < 2; ++j) {
    int hnrow = wn * 32 + j * 16 + lr;
#pragma unroll
    for (int ks = 0; ks < 2; ++ks) {
      int c16 = ks * 4 + kg;
      oB[j][ks] = (hnrow * 8 + (c16 ^ (hnrow & 7))) * 16;
    }
  }

  auto stA = [&](int h, int d, int kt, int c) {
    int u = c * 512 + tid;                          // linear 16B slot in half
    int hrow = u >> 3, ps = u & 7;
    int lc = ps ^ (hrow & 7);                       // inverse swizzle on source
    int r = (hrow & 63) | ((hrow >> 6) << 7) | (h << 6);
    gload_lds16(A + (size_t)(m0 + r) * K + kt * 64 + lc * 8,
                &sA[h][d][(size_t)u * 8]);
  };
  auto stB = [&](int h, int d, int kt, int c) {
    int u = c * 512 + tid;
    int hnrow = u >> 3, ps = u & 7;
    int lc = ps ^ (hnrow & 7);
    int n = (hnrow & 31) | ((hnrow >> 5) << 6) | (h << 5);
    gload_lds16(BT + (size_t)(n0 + n) * K + kt * 64 + lc * 8,
                &sB[h][d][(size_t)u * 8]);
  };

  // prologue: Ah0(0),Ah1(0),Bh0(0),Bh1(0),Ah0(1); vmcnt(4) leaves last 2 halves flying
  stA(0, 0, 0, 0); stA(0, 0, 0, 1);
  stA(1, 0, 0, 0); stA(1, 0, 0, 1);
  stB(0, 0, 0, 0); stB(0, 0, 0, 1);
  stB(1, 0, 0, 0); stB(1, 0, 0, 1);
  stA(0, 1, 1, 0); stA(0, 1, 1, 1);
  asm volatile("s_waitcnt vmcnt(4)\n\ts_barrier" ::: "memory");

  for (int t = 0; t < KT; ++t) {
    const int d = t & 1, dn = d ^ 1;
    const char* a0 = (const char*)&sA[0][d][0];
    const char* a1 = (const char*)&sA[1][d][0];
    const char* b0 = (const char*)&sB[0][d][0];
    const char* b1 = (const char*)&sB[1][d][0];
    const bool tail = (t >= KT - 2);

    bf16x8 afl[4][2], afh[4][2], bfl[2][2], bfh[2][2];

    // ---------- phase 1 ----------
#pragma unroll
    for (int i = 0; i < 4; ++i)
#pragma unroll
      for (int ks = 0; ks < 2; ++ks) afl[i][ks] = *(const bf16x8*)(a0 + oA[i][ks]);
#pragma unroll
    for (int j = 0; j < 2; ++j)
#pragma unroll
      for (int ks = 0; ks < 2; ++ks) bfl[j][ks] = *(const bf16x8*)(b0 + oB[j][ks]);
    if (t + 1 < KT) { stA(1, dn, t + 1, 0); stA(1, dn, t + 1, 1);
                      stB(0, dn, t + 1, 0); stB(0, dn, t + 1, 1); }
    asm volatile("s_barrier" ::: "memory");
    __builtin_amdgcn_s_setprio(1);
#pragma unroll
    for (int i = 0; i < 4; ++i)
#pragma unroll
      for (int j = 0; j < 2; ++j)
#pragma unroll
        for (int ks = 0; ks < 2; ++ks)
          acc[i][j] = mfma16(afl[i][ks], bfl[j][ks], acc[i][j]);
    __builtin_amdgcn_s_setprio(0);
    if (!tail) asm volatile("s_waitcnt vmcnt(4)\n\ts_barrier" ::: "memory");
    else       asm volatile("s_waitcnt vmcnt(0)\n\ts_barrier" ::: "memory");

    // ---------- phase 2 ----------
#pragma unroll
    for (int j = 0; j < 2; ++j)
#pragma unroll
      for (int ks = 0; ks < 2; ++ks) bfh[j][ks] = *(const bf16x8*)(b1 + oB[j][ks]);
    if (t + 1 < KT) { stB(1, dn, t + 1, 0); stB(1, dn, t + 1, 1); }
    asm volatile("s_barrier" ::: "memory");
    __builtin_amdgcn_s_setprio(1);
#pragma unroll
    for (int i = 0; i < 4; ++i)
#pragma unroll
      for (int j = 0; j < 2; ++j)
#pragma unroll
        for (int ks = 0; ks < 2; ++ks)
          acc[i][2 + j] = mfma16(afl[i][ks], bfh[j][ks], acc[i][2 + j]);
    __builtin_amdgcn_s_setprio(0);
    asm volatile("s_barrier" ::: "memory");

    // ---------- phase 3 ----------
#pragma unroll
    for (int i = 0; i < 4; ++i)
#pragma unroll
      for (int ks = 0; ks < 2; ++ks) afh[i][ks] = *(const bf16x8*)(a1 + oA[i][ks]);
    if (t + 2 < KT) { stA(0, d, t + 2, 0); stA(0, d, t + 2, 1); }
    asm volatile("s_barrier" ::: "memory");
    __builtin_amdgcn_s_setprio(1);
#pragma unroll
    for (int i = 0; i < 4; ++i)
#pragma unroll
      for (int j = 0; j < 2; ++j)
#pragma unroll
        for (int ks = 0; ks < 2; ++ks)
          acc[4 + i][2 + j] = mfma16(afh[i][ks], bfh[j][ks], acc[4 + i][2 + j]);
    __builtin_amdgcn_s_setprio(0);
    asm volatile("s_barrier" ::: "memory");

    // ---------- phase 4 (no reads, no stages) ----------
    asm volatile("s_barrier" ::: "memory");
    __builtin_amdgcn_s_setprio(1);
#pragma unroll
    for (int i = 0; i < 4; ++i)
#pragma unroll
      for (int j = 0; j < 2; ++j)
#pragma unroll
        for (int ks = 0; ks < 2; ++ks)
          acc[4 + i][j] = mfma16(afh[i][ks], bfl[j][ks], acc[4 + i][j]);
    __builtin_amdgcn_s_setprio(0);
    if (!tail) asm volatile("s_waitcnt vmcnt(4)\n\ts_barrier" ::: "memory");
    else       asm volatile("s_waitcnt vmcnt(0)\n\ts_barrier" ::: "memory");
  }

  // ---- epilogue ----
  const int cb = n0 >> 10;          // uniform per block (256 | 1024)
#pragma unroll
  for (int i = 0; i < 8; ++i) {
#pragma unroll
    for (int jj = 0; jj < 4; ++jj) {
      const int n = n0 + wn * 64 + jj * 16 + lr;
      const int m0r = m0 + wm * 128 + i * 16 + kg * 4;
      if (MODE == 0) {
        const int nn = n & 1023;
        if (cb == 0) {
          const float b_ = bias0[nn];
#pragma unroll
          for (int r = 0; r < 4; ++r)
            Qo[(size_t)(m0r + r) * ADIM + nn] = (bf16)(acc[i][jj][r] + b_);
        } else if (cb == 1) {
          const float b_ = bias1[nn];
#pragma unroll
          for (int r = 0; r < 4; ++r) {
            float v = acc[i][jj][r] + b_;
            Ko[(size_t)(m0r + r) * ADIM + nn] = (bf16)(v > 0.f ? v + 1.f : __expf(v));
          }
        } else {
          const float b_ = bias2[nn];
          const int bb = m0r >> 11, t0c = m0r & 2047;
          bf16x4 pk;
#pragma unroll
          for (int r = 0; r < 4; ++r) pk[r] = (bf16)(acc[i][jj][r] + b_);
          *(bf16x4*)&Vto[((size_t)bb * ADIM + nn) * ASEQ + t0c] = pk;
        }
      } else {
        const float b_ = bias0[n];
#pragma unroll
        for (int r = 0; r < 4; ++r)
          outF[(size_t)(m0r + r) * ADIM + n] = acc[i][jj][r] + b_;
      }
    }
  }
}

// --------- windowed decay attention: one (batch, 64-row q-tile) per WG ---------
__global__ __launch_bounds__(256) void k_attn(
    const bf16* __restrict__ Qg, const bf16* __restrict__ Kg,
    const bf16* __restrict__ Vt, bf16* __restrict__ Rb,
    const float* __restrict__ decay_param)
{
  const int b = blockIdx.y;
  const int T0 = blockIdx.x * 64;
  const int tid = threadIdx.x;
  const int l = tid & 63, w = tid >> 6;
  const int lr = l & 15, lk = (l >> 4) * 8;

  const float dp = decay_param[0];
  const float decay = 1.f / (1.f + __expf(-dp));
  const float l2d = __log2f(decay);

  __shared__ alignas(16) bf16 lQ[2][64 * 32];
  __shared__ alignas(16) bf16 lK[2][128 * 32];
  __shared__ alignas(16) bf16 lV[2][128 * 32];
  __shared__ alignas(16) bf16 lP[64 * 136];

  const bf16* Qb = Qg + (size_t)(b * ASEQ + T0) * ADIM;

  auto stageQK = [&](int buf, int k0) {
    {
      const bf16* g = Qb + (size_t)(w * 16 + (l >> 2)) * ADIM + k0 + (l & 3) * 8;
      gload_lds16(g, &lQ[buf][w * 16 * 32]);
    }
#pragma unroll
    for (int cc = 0; cc < 2; ++cc) {
      int c = 2 * w + cc;
      int sg = T0 - 64 + c * 16 + (l >> 2);
      if (sg < 0) sg = 0;
      const bf16* g = Kg + (size_t)(b * ASEQ + sg) * ADIM + k0 + (l & 3) * 8;
      gload_lds16(g, &lK[buf][c * 16 * 32]);
    }
  };

  f32x4 sc[4][2] = {};
  stageQK(0, 0);
  __syncthreads();
  for (int kt = 0; kt < 32; ++kt) {
    int cur = kt & 1;
    if (kt + 1 < 32) stageQK(cur ^ 1, (kt + 1) * 32);
    bf16x8 af[4], bfr[2];
#pragma unroll
    for (int i = 0; i < 4; ++i)
      af[i] = *(const bf16x8*)&lQ[cur][(i * 16 + lr) * 32 + lk];
#pragma unroll
    for (int j = 0; j < 2; ++j)
      bfr[j] = *(const bf16x8*)&lK[cur][(w * 32 + j * 16 + lr) * 32 + lk];
#pragma unroll
    for (int i = 0; i < 4; ++i)
#pragma unroll
      for (int j = 0; j < 2; ++j)
        sc[i][j] = mfma16(af[i], bfr[j], sc[i][j]);
    __syncthreads();
  }

  const int er = (l >> 4) * 4, ec = l & 15;
#pragma unroll
  for (int i = 0; i < 4; ++i)
#pragma unroll
    for (int j = 0; j < 2; ++j)
#pragma unroll
      for (int r = 0; r < 4; ++r) {
        int tl = i * 16 + er + r;
        int sl = w * 32 + j * 16 + ec;
        int sg = T0 - 64 + sl;
        int delta = (T0 + tl) - 1 - sg;
        float wgt = (delta >= 0 && delta < 64 && sg >= 0)
                        ? exp2f((float)delta * l2d) : 0.f;
        lP[tl * 136 + sl] = (bf16)(sc[i][j][r] * wgt);
      }

  auto stageV = [&](int buf, int g) {
    int nc = g >> 2, ks = g & 3;
#pragma unroll
    for (int cc = 0; cc < 2; ++cc) {
      int c = 2 * w + cc;
      int drow = nc * 128 + c * 16 + (l >> 2);
      int scol = T0 - 64 + ks * 32 + (l & 3) * 8;
      if (scol < 0) scol = 0;
      const bf16* gv = Vt + ((size_t)b * ADIM + drow) * ASEQ + scol;
      gload_lds16(gv, &lV[buf][c * 16 * 32]);
    }
  };

  f32x4 o[4][2] = {};
  stageV(0, 0);
  __syncthreads();

  for (int g = 0; g < 32; ++g) {
    int cur = g & 1;
    if (g + 1 < 32) stageV(cur ^ 1, g + 1);
    int nc = g >> 2, ks = g & 3;
    bf16x8 af[4], bfr[2];
#pragma unroll
    for (int i = 0; i < 4; ++i)
      af[i] = *(const bf16x8*)&lP[(i * 16 + lr) * 136 + ks * 32 + lk];
#pragma unroll
    for (int j = 0; j < 2; ++j)
      bfr[j] = *(const bf16x8*)&lV[cur][(w * 32 + j * 16 + lr) * 32 + lk];
#pragma unroll
    for (int i = 0; i < 4; ++i)
#pragma unroll
      for (int j = 0; j < 2; ++j)
        o[i][j] = mfma16(af[i], bfr[j], o[i][j]);
    if (ks == 3) {
#pragma unroll
      for (int i = 0; i < 4; ++i)
#pragma unroll
        for (int j = 0; j < 2; ++j) {
#pragma unroll
          for (int r = 0; r < 4; ++r) {
            int tl = i * 16 + er + r;
            int dl = nc * 128 + w * 32 + j * 16 + ec;
            Rb[(size_t)(b * ASEQ + T0 + tl) * ADIM + dl] = (bf16)o[i][j][r];
          }
#pragma unroll
          for (int r = 0; r < 4; ++r) o[i][j][r] = 0.f;
        }
    }
    __syncthreads();
  }
}

extern "C" void kernel_launch(void* const* d_in, const int* in_sizes, int n_in,
                              void* d_out, int out_size, void* d_ws, size_t ws_size,
                              hipStream_t stream) {
  const float* x  = (const float*)d_in[0];
  const float* Wq = (const float*)d_in[1];
  const float* bq = (const float*)d_in[2];
  const float* Wk = (const float*)d_in[3];
  const float* bk = (const float*)d_in[4];
  const float* Wv = (const float*)d_in[5];
  const float* bv = (const float*)d_in[6];
  const float* Wo = (const float*)d_in[7];
  const float* bo = (const float*)d_in[8];
  const float* dp = (const float*)d_in[9];
  float* out = (float*)d_out;

  char* ws = (char*)d_ws;
  bf16* Xb  = (bf16*)(ws + ((size_t)0 << 20));    // [16384][1024]
  bf16* Qb  = (bf16*)(ws + ((size_t)32 << 20));
  bf16* Kb  = (bf16*)(ws + ((size_t)64 << 20));
  bf16* Vtb = (bf16*)(ws + ((size_t)96 << 20));   // [8][1024][2048]
  bf16* Rbb = (bf16*)(ws + ((size_t)128 << 20));
  bf16* WcT = (bf16*)(ws + ((size_t)160 << 20));  // [3072][1024]
  bf16* WoT = (bf16*)(ws + ((size_t)166 << 20));  // [1024][1024]

  const int M = ABATCH * ASEQ;  // 16384

  k_prep<<<3072, 256, 0, stream>>>(x, Xb, (M * ADIM) / 4,
                                   Wq, Wk, Wv, Wo, WcT, WoT);
  k_g8<0><<<768, 512, 0, stream>>>(
      Xb, WcT, bq, bk, bv, Qb, Kb, Vtb, nullptr, 12);
  k_attn<<<dim3(32, 8), 256, 0, stream>>>(Qb, Kb, Vtb, Rbb, dp);
  k_g8<1><<<256, 512, 0, stream>>>(
      Rbb, WoT, bo, nullptr, nullptr, nullptr, nullptr, nullptr, out, 4);
}